// Round 1
// baseline (2147.411 us; speedup 1.0000x reference)
//
#include <hip/hip_runtime.h>
#include <cstdint>
#include <cstddef>

#define NNODES 10000
#define HDIM 64
#define BDIM 2
#define INDIM 128
#define TSTEPS 50

__device__ __forceinline__ float sigmoidf_(float x){ return 1.0f/(1.0f+__expf(-x)); }
__device__ __forceinline__ float tanhf_(float x){ float e=__expf(2.0f*x); return 1.0f-2.0f/(e+1.0f); }

__global__ void hist_kernel(const int* __restrict__ src, const int* __restrict__ dst,
                            int* __restrict__ deg_out, int* __restrict__ deg_in, int E){
  int e = blockIdx.x*blockDim.x + threadIdx.x;
  if (e < E){
    atomicAdd(&deg_out[src[e]], 1);
    atomicAdd(&deg_in[dst[e]], 1);
  }
}

// single block, 256 threads: exclusive prefix sum of deg_in -> row_off, cursor; norms.
__global__ void scan_kernel(const int* __restrict__ deg_in, const int* __restrict__ deg_out,
                            int* __restrict__ row_off, int* __restrict__ cursor,
                            float* __restrict__ norm_s, float* __restrict__ norm_d){
  __shared__ int part[256];
  int tid = threadIdx.x;
  const int CH = (NNODES + 255)/256;   // 40
  int base = tid*CH;
  int local = 0;
  for (int k=0;k<CH;k++){ int n=base+k; if(n<NNODES) local += deg_in[n]; }
  part[tid]=local;
  __syncthreads();
  if (tid==0){
    int run=0;
    for(int i=0;i<256;i++){ int t=part[i]; part[i]=run; run+=t; }
  }
  __syncthreads();
  int run = part[tid];
  for (int k=0;k<CH;k++){
    int n=base+k;
    if (n<NNODES){
      row_off[n]=run; cursor[n]=run;
      int di = deg_in[n]; run += di;
      norm_d[n] = rsqrtf(fmaxf((float)di,1.0f));
      norm_s[n] = rsqrtf(fmaxf((float)deg_out[n],1.0f));
    }
  }
  if (tid==255) row_off[NNODES]=run;   // == E
}

__global__ void fill_kernel(const int* __restrict__ src, const int* __restrict__ dst,
                            int* __restrict__ cursor, const float* __restrict__ norm_s,
                            int2* __restrict__ csr, int E){
  int e = blockIdx.x*blockDim.x + threadIdx.x;
  if (e<E){
    int d = dst[e]; int s = src[e];
    int pos = atomicAdd(&cursor[d],1);
    csr[pos] = make_int2(s, __float_as_int(norm_s[s]));
  }
}

// xproj layout: float2[3*64]: [gate][i] -> (b0, b1)
__global__ void xproj_kernel(const float* __restrict__ x,
                             const float* __restrict__ wr, const float* __restrict__ br,
                             const float* __restrict__ wz, const float* __restrict__ bz,
                             const float* __restrict__ wh, const float* __restrict__ bh,
                             float* __restrict__ xproj){
  int tid = threadIdx.x;             // 0..383
  if (tid >= 384) return;
  int g = tid >> 7; int r = tid & 127; int b = r >> 6; int i = r & 63;
  const float* w  = (g==0)?wr:(g==1)?wz:wh;
  const float* bb = (g==0)?br:(g==1)?bz:bh;
  float s = bb[i];
  for (int k=0;k<INDIM;k++) s = fmaf(x[b*INDIM+k], w[k*HDIM+i], s);
  xproj[g*128 + i*2 + b] = s;
}

// one wave per node-group; 4 nodes per wave; lane = H index; float2 = (b0,b1)
__launch_bounds__(256)
__global__ void step_kernel(const float2* __restrict__ h_in, float2* __restrict__ h_out,
                            float* __restrict__ out, int t,
                            const int* __restrict__ row_off, const int2* __restrict__ csr,
                            const float* __restrict__ norm_d,
                            const float* __restrict__ gcn_w, const float* __restrict__ gcn_b,
                            const float2* __restrict__ xproj){
  const int lane = threadIdx.x & 63;
  const int wv   = threadIdx.x >> 6;           // 0..3
  const int wave_g = blockIdx.x*4 + wv;        // 0..2499

  // W column for this lane: wreg[j] = W[j][lane]
  float wreg[64];
  #pragma unroll
  for (int j=0;j<64;j++) wreg[j] = gcn_w[j*HDIM + lane];
  const float bias = gcn_b[lane];
  const float2 xrv = xproj[lane];
  const float2 xzv = xproj[64+lane];
  const float2 xhv = xproj[128+lane];

  __shared__ float2 aggS[4][64];
  const size_t NH = (size_t)NNODES*HDIM;

  for (int q=0;q<4;q++){
    int n = __builtin_amdgcn_readfirstlane(wave_g*4 + q);   // 0..9999
    int beg = row_off[n], end = row_off[n+1];
    float2 acc = make_float2(0.f,0.f);
    for (int e=beg;e<end;e++){
      int2 ed = csr[e];
      float cw = __int_as_float(ed.y);
      float2 hv = h_in[(size_t)ed.x*HDIM + lane];
      acc.x = fmaf(cw, hv.x, acc.x);
      acc.y = fmaf(cw, hv.y, acc.y);
    }
    float nd = norm_d[n];
    acc.x *= nd; acc.y *= nd;

    __syncthreads();                 // WAR: previous iteration's readers done
    aggS[wv][lane] = acc;
    __syncthreads();                 // RAW: writes visible

    float g0 = bias, g1 = bias;
    #pragma unroll
    for (int j=0;j<64;j++){
      float2 a = aggS[wv][j];        // broadcast read within wave
      g0 = fmaf(a.x, wreg[j], g0);
      g1 = fmaf(a.y, wreg[j], g1);
    }

    float2 hold = h_in[(size_t)n*HDIM + lane];
    float r0 = sigmoidf_(xrv.x + g0), r1 = sigmoidf_(xrv.y + g1);
    float z0 = sigmoidf_(xzv.x + g0), z1 = sigmoidf_(xzv.y + g1);
    float t0 = tanhf_(xhv.x + r0*g0), t1 = tanhf_(xhv.y + r1*g1);
    float hn0 = hold.x + z0*(t0 - hold.x);
    float hn1 = hold.y + z1*(t1 - hold.y);
    h_out[(size_t)n*HDIM + lane] = make_float2(hn0,hn1);
    size_t idx = (size_t)t*NH + (size_t)n*HDIM + lane;
    out[idx] = hn0;                  // b=0 plane
    out[(size_t)TSTEPS*NH + idx] = hn1;  // b=1 plane
  }
}

extern "C" void kernel_launch(void* const* d_in, const int* in_sizes, int n_in,
                              void* d_out, int out_size, void* d_ws, size_t ws_size,
                              hipStream_t stream){
  const float* x   = (const float*)d_in[0];
  const int*   src = (const int*)d_in[1];
  const int*   dst = (const int*)d_in[2];
  const float* wr  = (const float*)d_in[3];
  const float* br  = (const float*)d_in[4];
  const float* wz  = (const float*)d_in[5];
  const float* bz  = (const float*)d_in[6];
  const float* wh  = (const float*)d_in[7];
  const float* bh  = (const float*)d_in[8];
  const float* gw  = (const float*)d_in[9];
  const float* gb  = (const float*)d_in[10];
  float* out = (float*)d_out;
  const int E = in_sizes[1];

  char* ws = (char*)d_ws;
  size_t o = 0;
  int*   deg_out = (int*)(ws+o);  o += 10240*4;
  int*   deg_in  = (int*)(ws+o);  o += 10240*4;
  int*   cursor  = (int*)(ws+o);  o += 10240*4;
  int*   row_off = (int*)(ws+o);  o += 10256*4;
  float* norm_s  = (float*)(ws+o); o += 10240*4;
  float* norm_d  = (float*)(ws+o); o += 10240*4;
  int2*  csr     = (int2*)(ws+o);  o += (size_t)E*8;
  float2* xproj  = (float2*)(ws+o); o += 256*8;
  o = (o + 255) & ~(size_t)255;
  float2* h0 = (float2*)(ws+o); o += (size_t)NNODES*HDIM*sizeof(float2);
  float2* h1 = (float2*)(ws+o); o += (size_t)NNODES*HDIM*sizeof(float2);

  // zero degree histograms (contiguous) and h0
  hipMemsetAsync(deg_out, 0, 2*10240*4, stream);
  hipMemsetAsync(h0, 0, (size_t)NNODES*HDIM*sizeof(float2), stream);

  int eb = (E+255)/256;
  hist_kernel<<<eb,256,0,stream>>>(src,dst,deg_out,deg_in,E);
  scan_kernel<<<1,256,0,stream>>>(deg_in,deg_out,row_off,cursor,norm_s,norm_d);
  fill_kernel<<<eb,256,0,stream>>>(src,dst,cursor,norm_s,csr,E);
  xproj_kernel<<<1,384,0,stream>>>(x,wr,br,wz,bz,wh,bh,(float*)xproj);

  float2* hin = h0; float2* hout = h1;
  for (int t=0;t<TSTEPS;t++){
    step_kernel<<<625,256,0,stream>>>(hin,hout,out,t,row_off,csr,norm_d,gw,gb,xproj);
    float2* tmp = hin; hin = hout; hout = tmp;
  }
}

// Round 2
// 1849.078 us; speedup vs baseline: 1.1613x; 1.1613x over previous
//
#include <hip/hip_runtime.h>
#include <cstdint>
#include <cstddef>

#define NNODES 10000
#define HDIM 64
#define BDIM 2
#define INDIM 128
#define TSTEPS 50

__device__ __forceinline__ float sigmoidf_(float x){ return 1.0f/(1.0f+__expf(-x)); }
__device__ __forceinline__ float tanhf_(float x){ float e=__expf(2.0f*x); return 1.0f-2.0f/(e+1.0f); }

__global__ void hist_kernel(const int* __restrict__ src, const int* __restrict__ dst,
                            int* __restrict__ deg_out, int* __restrict__ deg_in, int E){
  int e = blockIdx.x*blockDim.x + threadIdx.x;
  if (e < E){
    atomicAdd(&deg_out[src[e]], 1);
    atomicAdd(&deg_in[dst[e]], 1);
  }
}

// single block, 256 threads: exclusive prefix sum of deg_in -> row_off, cursor; norms.
__global__ void scan_kernel(const int* __restrict__ deg_in, const int* __restrict__ deg_out,
                            int* __restrict__ row_off, int* __restrict__ cursor,
                            float* __restrict__ norm_s, float* __restrict__ norm_d){
  __shared__ int part[256];
  int tid = threadIdx.x;
  const int CH = (NNODES + 255)/256;   // 40
  int base = tid*CH;
  int local = 0;
  for (int k=0;k<CH;k++){ int n=base+k; if(n<NNODES) local += deg_in[n]; }
  part[tid]=local;
  __syncthreads();
  if (tid==0){
    int run=0;
    for(int i=0;i<256;i++){ int t=part[i]; part[i]=run; run+=t; }
  }
  __syncthreads();
  int run = part[tid];
  for (int k=0;k<CH;k++){
    int n=base+k;
    if (n<NNODES){
      row_off[n]=run; cursor[n]=run;
      int di = deg_in[n]; run += di;
      norm_d[n] = rsqrtf(fmaxf((float)di,1.0f));
      norm_s[n] = rsqrtf(fmaxf((float)deg_out[n],1.0f));
    }
  }
  if (tid==255) row_off[NNODES]=run;   // == E
}

__global__ void fill_kernel(const int* __restrict__ src, const int* __restrict__ dst,
                            int* __restrict__ cursor, const float* __restrict__ norm_s,
                            int2* __restrict__ csr, int E){
  int e = blockIdx.x*blockDim.x + threadIdx.x;
  if (e<E){
    int d = dst[e]; int s = src[e];
    int pos = atomicAdd(&cursor[d],1);
    csr[pos] = make_int2(s, __float_as_int(norm_s[s]));
  }
}

// xproj layout: float2[3*64]: [gate][i] -> (b0, b1)
__global__ void xproj_kernel(const float* __restrict__ x,
                             const float* __restrict__ wr, const float* __restrict__ br,
                             const float* __restrict__ wz, const float* __restrict__ bz,
                             const float* __restrict__ wh, const float* __restrict__ bh,
                             float* __restrict__ xproj){
  int tid = threadIdx.x;             // 0..383
  if (tid >= 384) return;
  int g = tid >> 7; int r = tid & 127; int b = r >> 6; int i = r & 63;
  const float* w  = (g==0)?wr:(g==1)?wz:wh;
  const float* bb = (g==0)?br:(g==1)?bz:bh;
  float s = bb[i];
  for (int k=0;k<INDIM;k++) s = fmaf(x[b*INDIM+k], w[k*HDIM+i], s);
  xproj[g*128 + i*2 + b] = s;
}

// transpose gcn_w (64x64, row-major W[j][i]) into wT[i*64+j] so each lane's
// column is contiguous -> 16x float4 loads per wave.
__global__ void transpose_w_kernel(const float* __restrict__ gcn_w, float* __restrict__ wT){
  int tid = threadIdx.x;                  // 256 threads, 16 elems each
  for (int k=0;k<16;k++){
    int idx = tid*16 + k;                 // 0..4095
    int i = idx >> 6, j = idx & 63;       // wT[i][j]
    wT[idx] = gcn_w[j*HDIM + i];
  }
}

// one wave per node; lane = H index; float2 = (b0,b1). No __syncthreads:
// agg broadcast goes through a per-wave LDS slot (wave-internal LDS ordering).
__launch_bounds__(256, 4)
__global__ void step_kernel(const float2* __restrict__ h_in, float2* __restrict__ h_out,
                            float* __restrict__ out, int t,
                            const int* __restrict__ row_off, const int2* __restrict__ csr,
                            const float* __restrict__ norm_d,
                            const float* __restrict__ wT, const float* __restrict__ gcn_b,
                            const float2* __restrict__ xproj){
  const int lane = threadIdx.x & 63;
  const int wv   = threadIdx.x >> 6;                 // 0..3
  const int n    = __builtin_amdgcn_readfirstlane(blockIdx.x*4 + wv); // 0..9999

  // W column for this lane: wreg[j] = W[j][lane] = wT[lane*64+j], contiguous
  float wreg[64];
  {
    const float4* wp = (const float4*)(wT + (size_t)lane*64);
    #pragma unroll
    for (int j=0;j<16;j++){
      float4 w4 = wp[j];
      wreg[4*j+0]=w4.x; wreg[4*j+1]=w4.y; wreg[4*j+2]=w4.z; wreg[4*j+3]=w4.w;
    }
  }
  const float bias = gcn_b[lane];
  const float2 xrv = xproj[lane];
  const float2 xzv = xproj[64+lane];
  const float2 xhv = xproj[128+lane];

  int beg = __builtin_amdgcn_readfirstlane(row_off[n]);
  int end = __builtin_amdgcn_readfirstlane(row_off[n+1]);

  // issue h_old load early
  float2 hold = h_in[(size_t)n*HDIM + lane];

  float2 a0=make_float2(0.f,0.f), a1=a0, a2=a0, a3=a0;
  int e = beg;
  for (; e+4 <= end; e+=4){
    int2 c0=csr[e], c1=csr[e+1], c2=csr[e+2], c3=csr[e+3];
    float2 v0 = h_in[(size_t)c0.x*HDIM + lane];
    float2 v1 = h_in[(size_t)c1.x*HDIM + lane];
    float2 v2 = h_in[(size_t)c2.x*HDIM + lane];
    float2 v3 = h_in[(size_t)c3.x*HDIM + lane];
    float w0=__int_as_float(c0.y), w1=__int_as_float(c1.y);
    float w2=__int_as_float(c2.y), w3=__int_as_float(c3.y);
    a0.x=fmaf(w0,v0.x,a0.x); a0.y=fmaf(w0,v0.y,a0.y);
    a1.x=fmaf(w1,v1.x,a1.x); a1.y=fmaf(w1,v1.y,a1.y);
    a2.x=fmaf(w2,v2.x,a2.x); a2.y=fmaf(w2,v2.y,a2.y);
    a3.x=fmaf(w3,v3.x,a3.x); a3.y=fmaf(w3,v3.y,a3.y);
  }
  for (; e < end; e++){
    int2 c0=csr[e];
    float2 v0 = h_in[(size_t)c0.x*HDIM + lane];
    float w0=__int_as_float(c0.y);
    a0.x=fmaf(w0,v0.x,a0.x); a0.y=fmaf(w0,v0.y,a0.y);
  }
  float nd = norm_d[n];
  float2 acc = make_float2((a0.x+a1.x)+(a2.x+a3.x), (a0.y+a1.y)+(a2.y+a3.y));
  acc.x *= nd; acc.y *= nd;

  __shared__ float2 aggS[4][64];
  aggS[wv][lane] = acc;
  __asm__ volatile("s_waitcnt lgkmcnt(0)" ::: "memory");  // wave-private slot; order write->reads

  float g0 = bias, g1 = bias;
  #pragma unroll
  for (int j=0;j<64;j++){
    float2 a = aggS[wv][j];            // same-address broadcast: conflict-free
    g0 = fmaf(a.x, wreg[j], g0);
    g1 = fmaf(a.y, wreg[j], g1);
  }

  float r0 = sigmoidf_(xrv.x + g0), r1 = sigmoidf_(xrv.y + g1);
  float z0 = sigmoidf_(xzv.x + g0), z1 = sigmoidf_(xzv.y + g1);
  float t0 = tanhf_(xhv.x + r0*g0), t1 = tanhf_(xhv.y + r1*g1);
  float hn0 = hold.x + z0*(t0 - hold.x);
  float hn1 = hold.y + z1*(t1 - hold.y);

  const size_t NH = (size_t)NNODES*HDIM;
  h_out[(size_t)n*HDIM + lane] = make_float2(hn0,hn1);
  size_t idx = (size_t)t*NH + (size_t)n*HDIM + lane;
  out[idx] = hn0;                           // b=0 plane
  out[(size_t)TSTEPS*NH + idx] = hn1;       // b=1 plane
}

extern "C" void kernel_launch(void* const* d_in, const int* in_sizes, int n_in,
                              void* d_out, int out_size, void* d_ws, size_t ws_size,
                              hipStream_t stream){
  const float* x   = (const float*)d_in[0];
  const int*   src = (const int*)d_in[1];
  const int*   dst = (const int*)d_in[2];
  const float* wr  = (const float*)d_in[3];
  const float* br  = (const float*)d_in[4];
  const float* wz  = (const float*)d_in[5];
  const float* bz  = (const float*)d_in[6];
  const float* wh  = (const float*)d_in[7];
  const float* bh  = (const float*)d_in[8];
  const float* gw  = (const float*)d_in[9];
  const float* gb  = (const float*)d_in[10];
  float* out = (float*)d_out;
  const int E = in_sizes[1];

  char* ws = (char*)d_ws;
  size_t o = 0;
  int*   deg_out = (int*)(ws+o);  o += 10240*4;
  int*   deg_in  = (int*)(ws+o);  o += 10240*4;
  int*   cursor  = (int*)(ws+o);  o += 10240*4;
  int*   row_off = (int*)(ws+o);  o += 10256*4;
  float* norm_s  = (float*)(ws+o); o += 10240*4;
  float* norm_d  = (float*)(ws+o); o += 10240*4;
  int2*  csr     = (int2*)(ws+o);  o += (size_t)E*8;
  float* xproj   = (float*)(ws+o); o += 512*4;
  float* wT      = (float*)(ws+o); o += 4096*4;
  o = (o + 255) & ~(size_t)255;
  float2* h0 = (float2*)(ws+o); o += (size_t)NNODES*HDIM*sizeof(float2);
  float2* h1 = (float2*)(ws+o); o += (size_t)NNODES*HDIM*sizeof(float2);

  hipMemsetAsync(deg_out, 0, 2*10240*4, stream);
  hipMemsetAsync(h0, 0, (size_t)NNODES*HDIM*sizeof(float2), stream);

  int eb = (E+255)/256;
  hist_kernel<<<eb,256,0,stream>>>(src,dst,deg_out,deg_in,E);
  scan_kernel<<<1,256,0,stream>>>(deg_in,deg_out,row_off,cursor,norm_s,norm_d);
  fill_kernel<<<eb,256,0,stream>>>(src,dst,cursor,norm_s,csr,E);
  xproj_kernel<<<1,384,0,stream>>>(x,wr,br,wz,bz,wh,bh,xproj);
  transpose_w_kernel<<<1,256,0,stream>>>(gw,wT);

  float2* hin = h0; float2* hout = h1;
  for (int t=0;t<TSTEPS;t++){
    step_kernel<<<2500,256,0,stream>>>(hin,hout,out,t,row_off,csr,norm_d,wT,gb,(const float2*)xproj);
    float2* tmp = hin; hin = hout; hout = tmp;
  }
}

// Round 3
// 1696.505 us; speedup vs baseline: 1.2658x; 1.0899x over previous
//
#include <hip/hip_runtime.h>
#include <cstdint>
#include <cstddef>

#define NNODES 10000
#define HDIM 64
#define BDIM 2
#define INDIM 128
#define TSTEPS 50

__device__ __forceinline__ float sigmoidf_(float x){ return 1.0f/(1.0f+__expf(-x)); }
__device__ __forceinline__ float tanhf_(float x){ float e=__expf(2.0f*x); return 1.0f-2.0f/(e+1.0f); }

__device__ __forceinline__ uint32_t pack_bf16x2(float a, float b){
  uint32_t ua = __float_as_uint(a), ub = __float_as_uint(b);
  ua = (ua + 0x7fffu + ((ua>>16)&1u)) >> 16;          // rne
  ub = (ub + 0x7fffu + ((ub>>16)&1u)) >> 16;
  return ua | (ub<<16);
}

__global__ void hist_kernel(const int* __restrict__ src, const int* __restrict__ dst,
                            int* __restrict__ deg_out, int* __restrict__ deg_in, int E){
  int e = blockIdx.x*blockDim.x + threadIdx.x;
  if (e < E){
    atomicAdd(&deg_out[src[e]], 1);
    atomicAdd(&deg_in[dst[e]], 1);
  }
}

__global__ void scan_kernel(const int* __restrict__ deg_in, const int* __restrict__ deg_out,
                            int* __restrict__ row_off, int* __restrict__ cursor,
                            float* __restrict__ norm_s, float* __restrict__ norm_d){
  __shared__ int part[256];
  int tid = threadIdx.x;
  const int CH = (NNODES + 255)/256;   // 40
  int base = tid*CH;
  int local = 0;
  for (int k=0;k<CH;k++){ int n=base+k; if(n<NNODES) local += deg_in[n]; }
  part[tid]=local;
  __syncthreads();
  if (tid==0){
    int run=0;
    for(int i=0;i<256;i++){ int t=part[i]; part[i]=run; run+=t; }
  }
  __syncthreads();
  int run = part[tid];
  for (int k=0;k<CH;k++){
    int n=base+k;
    if (n<NNODES){
      row_off[n]=run; cursor[n]=run;
      int di = deg_in[n]; run += di;
      norm_d[n] = rsqrtf(fmaxf((float)di,1.0f));
      norm_s[n] = rsqrtf(fmaxf((float)deg_out[n],1.0f));
    }
  }
  if (tid==255) row_off[NNODES]=run;   // == E
}

__global__ void fill_kernel(const int* __restrict__ src, const int* __restrict__ dst,
                            int* __restrict__ cursor, const float* __restrict__ norm_s,
                            int2* __restrict__ csr, int E){
  int e = blockIdx.x*blockDim.x + threadIdx.x;
  if (e<E){
    int d = dst[e]; int s = src[e];
    int pos = atomicAdd(&cursor[d],1);
    csr[pos] = make_int2(s, __float_as_int(norm_s[s]));
  }
}

__global__ void xproj_kernel(const float* __restrict__ x,
                             const float* __restrict__ wr, const float* __restrict__ br,
                             const float* __restrict__ wz, const float* __restrict__ bz,
                             const float* __restrict__ wh, const float* __restrict__ bh,
                             float* __restrict__ xproj){
  int tid = threadIdx.x;             // 0..383
  if (tid >= 384) return;
  int g = tid >> 7; int r = tid & 127; int b = r >> 6; int i = r & 63;
  const float* w  = (g==0)?wr:(g==1)?wz:wh;
  const float* bb = (g==0)?br:(g==1)?bz:bh;
  float s = bb[i];
  for (int k=0;k<INDIM;k++) s = fmaf(x[b*INDIM+k], w[k*HDIM+i], s);
  xproj[g*128 + i*2 + b] = s;
}

__global__ void transpose_w_kernel(const float* __restrict__ gcn_w, float* __restrict__ wT){
  int tid = threadIdx.x;                  // 256 threads, 16 elems each
  for (int k=0;k<16;k++){
    int idx = tid*16 + k;                 // 0..4095
    int i = idx >> 6, j = idx & 63;       // wT[i][j]
    wT[idx] = gcn_w[j*HDIM + i];
  }
}

// one wave per node; lane = H index. Gathers read packed-bf16 shadow of h
// (2.56 MB -> fits each XCD's 4 MiB L2); fp32 state path stays exact.
__launch_bounds__(256, 4)
__global__ void step_kernel(const float2* __restrict__ h_in, float2* __restrict__ h_out,
                            const uint32_t* __restrict__ hb_in, uint32_t* __restrict__ hb_out,
                            float* __restrict__ out, int t,
                            const int* __restrict__ row_off, const int2* __restrict__ csr,
                            const float* __restrict__ norm_d,
                            const float* __restrict__ wT, const float* __restrict__ gcn_b,
                            const float2* __restrict__ xproj){
  const int lane = threadIdx.x & 63;
  const int wv   = threadIdx.x >> 6;                 // 0..3
  const int n    = __builtin_amdgcn_readfirstlane(blockIdx.x*4 + wv); // 0..9999

  // W column for this lane: wreg[j] = W[j][lane] = wT[lane*64+j], contiguous
  float wreg[64];
  {
    const float4* wp = (const float4*)(wT + (size_t)lane*64);
    #pragma unroll
    for (int j=0;j<16;j++){
      float4 w4 = wp[j];
      wreg[4*j+0]=w4.x; wreg[4*j+1]=w4.y; wreg[4*j+2]=w4.z; wreg[4*j+3]=w4.w;
    }
  }
  const float bias = gcn_b[lane];
  const float2 xrv = xproj[lane];
  const float2 xzv = xproj[64+lane];
  const float2 xhv = xproj[128+lane];

  int beg = __builtin_amdgcn_readfirstlane(row_off[n]);
  int end = __builtin_amdgcn_readfirstlane(row_off[n+1]);

  float2 hold = h_in[(size_t)n*HDIM + lane];   // fp32 state, issued early

  float2 a0=make_float2(0.f,0.f), a1=a0, a2=a0, a3=a0;
  int e = beg;
  for (; e+4 <= end; e+=4){
    int2 c0=csr[e], c1=csr[e+1], c2=csr[e+2], c3=csr[e+3];
    uint32_t p0 = hb_in[(size_t)c0.x*HDIM + lane];
    uint32_t p1 = hb_in[(size_t)c1.x*HDIM + lane];
    uint32_t p2 = hb_in[(size_t)c2.x*HDIM + lane];
    uint32_t p3 = hb_in[(size_t)c3.x*HDIM + lane];
    float w0=__int_as_float(c0.y), w1=__int_as_float(c1.y);
    float w2=__int_as_float(c2.y), w3=__int_as_float(c3.y);
    a0.x=fmaf(w0,__uint_as_float(p0<<16),a0.x); a0.y=fmaf(w0,__uint_as_float(p0&0xffff0000u),a0.y);
    a1.x=fmaf(w1,__uint_as_float(p1<<16),a1.x); a1.y=fmaf(w1,__uint_as_float(p1&0xffff0000u),a1.y);
    a2.x=fmaf(w2,__uint_as_float(p2<<16),a2.x); a2.y=fmaf(w2,__uint_as_float(p2&0xffff0000u),a2.y);
    a3.x=fmaf(w3,__uint_as_float(p3<<16),a3.x); a3.y=fmaf(w3,__uint_as_float(p3&0xffff0000u),a3.y);
  }
  for (; e < end; e++){
    int2 c0=csr[e];
    uint32_t p0 = hb_in[(size_t)c0.x*HDIM + lane];
    float w0=__int_as_float(c0.y);
    a0.x=fmaf(w0,__uint_as_float(p0<<16),a0.x); a0.y=fmaf(w0,__uint_as_float(p0&0xffff0000u),a0.y);
  }
  float nd = norm_d[n];
  float2 acc = make_float2((a0.x+a1.x)+(a2.x+a3.x), (a0.y+a1.y)+(a2.y+a3.y));
  acc.x *= nd; acc.y *= nd;

  __shared__ float2 aggS[4][64];
  aggS[wv][lane] = acc;
  __asm__ volatile("s_waitcnt lgkmcnt(0)" ::: "memory");  // wave-private slot

  float g0 = bias, g1 = bias;
  #pragma unroll
  for (int j=0;j<64;j++){
    float2 a = aggS[wv][j];            // same-address broadcast: conflict-free
    g0 = fmaf(a.x, wreg[j], g0);
    g1 = fmaf(a.y, wreg[j], g1);
  }

  float r0 = sigmoidf_(xrv.x + g0), r1 = sigmoidf_(xrv.y + g1);
  float z0 = sigmoidf_(xzv.x + g0), z1 = sigmoidf_(xzv.y + g1);
  float t0 = tanhf_(xhv.x + r0*g0), t1 = tanhf_(xhv.y + r1*g1);
  float hn0 = hold.x + z0*(t0 - hold.x);
  float hn1 = hold.y + z1*(t1 - hold.y);

  const size_t NH = (size_t)NNODES*HDIM;
  h_out[(size_t)n*HDIM + lane] = make_float2(hn0,hn1);
  hb_out[(size_t)n*HDIM + lane] = pack_bf16x2(hn0,hn1);
  size_t idx = (size_t)t*NH + (size_t)n*HDIM + lane;
  out[idx] = hn0;                           // b=0 plane
  out[(size_t)TSTEPS*NH + idx] = hn1;       // b=1 plane
}

extern "C" void kernel_launch(void* const* d_in, const int* in_sizes, int n_in,
                              void* d_out, int out_size, void* d_ws, size_t ws_size,
                              hipStream_t stream){
  const float* x   = (const float*)d_in[0];
  const int*   src = (const int*)d_in[1];
  const int*   dst = (const int*)d_in[2];
  const float* wr  = (const float*)d_in[3];
  const float* br  = (const float*)d_in[4];
  const float* wz  = (const float*)d_in[5];
  const float* bz  = (const float*)d_in[6];
  const float* wh  = (const float*)d_in[7];
  const float* bh  = (const float*)d_in[8];
  const float* gw  = (const float*)d_in[9];
  const float* gb  = (const float*)d_in[10];
  float* out = (float*)d_out;
  const int E = in_sizes[1];

  char* ws = (char*)d_ws;
  size_t o = 0;
  int*   deg_out = (int*)(ws+o);  o += 10240*4;
  int*   deg_in  = (int*)(ws+o);  o += 10240*4;
  int*   cursor  = (int*)(ws+o);  o += 10240*4;
  int*   row_off = (int*)(ws+o);  o += 10256*4;
  float* norm_s  = (float*)(ws+o); o += 10240*4;
  float* norm_d  = (float*)(ws+o); o += 10240*4;
  int2*  csr     = (int2*)(ws+o);  o += (size_t)E*8;
  float* xproj   = (float*)(ws+o); o += 512*4;
  float* wT      = (float*)(ws+o); o += 4096*4;
  o = (o + 255) & ~(size_t)255;
  const size_t NHf2 = (size_t)NNODES*HDIM*sizeof(float2);   // 5.12 MB
  const size_t NHu  = (size_t)NNODES*HDIM*sizeof(uint32_t); // 2.56 MB
  float2*   h0  = (float2*)(ws+o);   o += NHf2;
  uint32_t* hb0 = (uint32_t*)(ws+o); o += NHu;   // contiguous with h0 -> one memset
  float2*   h1  = (float2*)(ws+o);   o += NHf2;
  uint32_t* hb1 = (uint32_t*)(ws+o); o += NHu;

  hipMemsetAsync(deg_out, 0, 2*10240*4, stream);
  hipMemsetAsync(h0, 0, NHf2 + NHu, stream);     // zeros h0 and hb0

  int eb = (E+255)/256;
  hist_kernel<<<eb,256,0,stream>>>(src,dst,deg_out,deg_in,E);
  scan_kernel<<<1,256,0,stream>>>(deg_in,deg_out,row_off,cursor,norm_s,norm_d);
  fill_kernel<<<eb,256,0,stream>>>(src,dst,cursor,norm_s,csr,E);
  xproj_kernel<<<1,384,0,stream>>>(x,wr,br,wz,bz,wh,bh,xproj);
  transpose_w_kernel<<<1,256,0,stream>>>(gw,wT);

  float2* hin = h0;  float2* hout = h1;
  uint32_t* hbin = hb0; uint32_t* hbout = hb1;
  for (int t=0;t<TSTEPS;t++){
    step_kernel<<<2500,256,0,stream>>>(hin,hout,hbin,hbout,out,t,row_off,csr,norm_d,wT,gb,(const float2*)xproj);
    float2* tf = hin; hin = hout; hout = tf;
    uint32_t* tb = hbin; hbin = hbout; hbout = tb;
  }
}